// Round 20
// baseline (118.528 us; speedup 1.0000x reference)
//
#include <hip/hip_runtime.h>
#include <hip/hip_bf16.h>

constexpr int kN = 8192;
constexpr int kD = 128;
constexpr int BM = 32;      // rows per block in main kernel (2 MFMA row-tiles)
constexpr int BK = 64;      // j-chunk (2 fragment windows)
constexpr int JSPLIT = 8;   // j-range strips (grid at 2048 blocks)
constexpr int LDB = 72;     // A-tile LDS row stride: 144B, 16B-aligned (r19-proven)
constexpr int TB = 64;      // rowsum tile
constexpr int NB = kN / TB; // 128

typedef __bf16 v8bf __attribute__((ext_vector_type(8)));
typedef float  v4f  __attribute__((ext_vector_type(4)));

// K_raw with 3 transcendentals (round-8 proven).
__device__ __forceinline__ float kraw_f(float4 ci, float sqi, float4 cj, float sqj) {
    float d2 = sqi + sqj - 2.0f * (ci.x * cj.x + ci.y * cj.y + ci.z * cj.z);
    d2 = fmaxf(d2, 1e-12f);
    float Dd = __builtin_amdgcn_sqrtf(d2);
    float a = 0.5f * (ci.w + cj.w);
    float t = a * (-0.5f * __builtin_amdgcn_logf(d2));                // -a*log2(D)
    t = fminf(fmaxf(t, -26.575424759098897f), 9.965784284662087f);   // log2(1e-8), log2(1000)
    float K = __builtin_amdgcn_exp2f(fmaf(Dd, -0.12022458674074695f, t));
    return fminf(K, 1000.0f);  // K >= 0 always
}

// --- kernel 1: pack coords+alpha into float4; zero rsum (r18 proven) -------
__global__ void pack_k(const float* __restrict__ coords, const float* __restrict__ alpha,
                       float4* __restrict__ c4, float* __restrict__ rsum) {
    int j = blockIdx.x * 256 + threadIdx.x;
    if (j < kN) {
        c4[j] = make_float4(coords[3 * j], coords[3 * j + 1], coords[3 * j + 2], alpha[j]);
        rsum[j] = 0.0f;   // consumed by rowsum_sym_k (later in stream order)
    }
}

// --- kernel 2: fragment-native B prep (r14 correctness-proven) -------------
// latTf: for 32-col window jw (0..255), d-tile d (0..7): contiguous 1KB =
// the 64-lane x 16B MFMA B-fragment: lane l holds
// latent[jw*32 + (l>>4)*8 + e][d*16 + (l&15)], e=0..7, bf16.
// Also zeroes outp (consumed by main_k later in stream order).
__global__ __launch_bounds__(256) void fragprep_k(const float* __restrict__ latent,
                                                  __bf16* __restrict__ latTf,
                                                  float* __restrict__ outp) {
    __shared__ float ltile[32][132];   // 32 j-rows x 128 dims (pad 4)
    const int jw = blockIdx.x;
    const int t = threadIdx.x;

    #pragma unroll
    for (int it = 0; it < 4; ++it) {
        int idx = it * 256 + t;            // 0..1023
        int row = idx >> 5;                // 0..31
        int col = (idx & 31) * 4;          // 0..124
        float4 v = *reinterpret_cast<const float4*>(
            latent + (size_t)(jw * 32 + row) * kD + col);
        *reinterpret_cast<float4*>(&ltile[row][col]) = v;
    }

    // zero outp: 256 blocks x 256 threads x 16 floats = kN*kD, bijective.
    {
        size_t base = ((size_t)jw * 256 + t) * 16;
        v4f z = {0.f, 0.f, 0.f, 0.f};
        #pragma unroll
        for (int e = 0; e < 4; ++e)
            *reinterpret_cast<v4f*>(outp + base + e * 4) = z;
    }
    __syncthreads();

    #pragma unroll
    for (int ss = 0; ss < 2; ++ss) {
        int s = ss * 256 + t;              // 0..511 fragment slots
        int d = s >> 6, l = s & 63;
        int jr = (l >> 4) * 8, dim = d * 16 + (l & 15);
        unsigned w[4];
        #pragma unroll
        for (int e2 = 0; e2 < 4; ++e2) {
            __bf16 lo = (__bf16)ltile[jr + 2 * e2][dim];
            __bf16 hi = (__bf16)ltile[jr + 2 * e2 + 1][dim];
            w[e2] = ((unsigned)*(unsigned short*)&hi << 16) | *(unsigned short*)&lo;
        }
        uint4 out = {w[0], w[1], w[2], w[3]};
        *reinterpret_cast<uint4*>((char*)latTf + (((size_t)jw * 8 + d) * 64 + l) * 16) = out;
    }
}

// --- kernel 3: SYMMETRIC row sums (round-11 proven) ------------------------
__global__ __launch_bounds__(256) void rowsum_sym_k(const float4* __restrict__ c4,
                                                    float* __restrict__ rsum) {
    __shared__ float4 rc4[TB];
    __shared__ float  rsq[TB];
    __shared__ float  rowbuf[TB][TB + 1];   // 16.25 KB

    // decode triangular pair (bi <= bj) from linear block index
    int L = blockIdx.x;
    int bi = (int)((2 * NB + 1 - sqrtf((float)((2 * NB + 1) * (2 * NB + 1) - 8 * L))) * 0.5f);
    #pragma unroll
    for (int f = 0; f < 2; ++f) {
        int s0 = bi * NB - bi * (bi - 1) / 2;
        int s1 = (bi + 1) * NB - (bi + 1) * bi / 2;
        if (L >= s1) ++bi;
        else if (L < s0) --bi;
    }
    int sbi = bi * NB - bi * (bi - 1) / 2;
    int bj = bi + (L - sbi);
    bool diag = (bi == bj);

    const int t = threadIdx.x;
    const int l = t & 63;
    const int w = t >> 6;

    if (t < TB) {
        float4 ci = c4[bi * TB + t];
        rc4[t] = ci;
        rsq[t] = ci.x * ci.x + ci.y * ci.y + ci.z * ci.z;
    }
    __syncthreads();

    float4 cj = c4[bj * TB + l];
    float sqj = cj.x * cj.x + cj.y * cj.y + cj.z * cj.z;

    float colacc = 0.f;
    #pragma unroll
    for (int rr = 0; rr < 16; ++rr) {
        int r = w * 16 + rr;
        float k = kraw_f(rc4[r], rsq[r], cj, sqj);
        if (diag && r == l) k = 0.f;
        colacc += k;
        rowbuf[r][l] = k;
    }
    __syncthreads();

    // row sums: thread t -> row r = t>>2, quarter q = t&3 (adjacent lanes)
    {
        int r = t >> 2, q = t & 3;
        float p = 0.f;
        #pragma unroll
        for (int m = 0; m < 16; ++m) p += rowbuf[r][q * 16 + m];
        p += __shfl_xor(p, 1, 64);
        p += __shfl_xor(p, 2, 64);
        if (q == 0) atomicAdd(&rsum[bi * TB + r], p);
    }
    if (!diag) atomicAdd(&rsum[bj * TB + l], colacc);
}

// --- kernel 4: fused K write + MFMA GEMM — r11 A-structure, LDS-free B -----
// A path byte-identical to r19 (kraw -> Kout -> Alds, two barriers). B comes
// straight from fragment-native latTf (L2-resident): one coalesced 16B load
// per MFMA, no LDS staging. LDS 21.8 -> 5.1 KB; occupancy cap 7 -> 8 blocks/CU.
__global__ __launch_bounds__(256, 2) void main_k(
    const float4* __restrict__ c4, const float* __restrict__ rsum,
    const __bf16* __restrict__ latTf, float* __restrict__ outp, float* __restrict__ Kout) {

    __shared__ __bf16 Alds[BM][LDB];    // 4.6 KB, normalized K tile
    __shared__ float4 c4row[BM];
    __shared__ float  sqrow[BM];
    __shared__ float  invrow[BM];

    const int t = threadIdx.x;
    const int i0 = blockIdx.x * BM;
    const int jstrip = blockIdx.y * (kN / JSPLIT);

    if (t < BM) {
        float4 ci = c4[i0 + t];
        c4row[t] = ci;
        sqrow[t] = ci.x * ci.x + ci.y * ci.y + ci.z * ci.z;
        invrow[t] = 1.0f / (rsum[i0 + t] + 1e-8f);
    }
    __syncthreads();

    const int lane = t & 63;
    const int wave = t >> 6;

    // K-tile compute mapping: col pair {2*c2, 2*c2+1}, rows rb..rb+3
    const int c2 = t & 31;
    const int rb = (t >> 5) * 4;

    // hoist this thread's 4 fixed rows into registers (r11-proven)
    float4 rc[4]; float rs[4], rv[4];
    #pragma unroll
    for (int rr = 0; rr < 4; ++rr) {
        rc[rr] = c4row[rb + rr];
        rs[rr] = sqrow[rb + rr];
        rv[rr] = invrow[rb + rr];
    }

    // MFMA fragment addressing (r9/r10-proven A; r14-proven B)
    const int arow = lane & 15;
    const int koff = (lane >> 4) * 8;          // elements
    // B fragment base for this lane: + (jw*8 + dtile)*1024 per fragment
    const char* bfb = (const char*)latTf + (size_t)lane * 16;

    v4f acc[2][2];
    #pragma unroll
    for (int rt = 0; rt < 2; ++rt)
        #pragma unroll
        for (int dt = 0; dt < 2; ++dt) acc[rt][dt] = (v4f){0.f, 0.f, 0.f, 0.f};

    for (int cb = 0; cb < kN / JSPLIT / BK; ++cb) {
        const int j0 = jstrip + cb * BK;

        // K tile (32 x 64): cols {gjA, gjB}, rows rb..rb+3; kraw once per elem
        const int gjA = j0 + 2 * c2, gjB = gjA + 1;
        const float4 cjA = c4[gjA];
        const float4 cjB = c4[gjB];
        const float sqA = cjA.x * cjA.x + cjA.y * cjA.y + cjA.z * cjA.z;
        const float sqB = cjB.x * cjB.x + cjB.y * cjB.y + cjB.z * cjB.z;
        #pragma unroll
        for (int rr = 0; rr < 4; ++rr) {
            int r = rb + rr, gi = i0 + r;
            float kA = (gi == gjA) ? 0.0f : kraw_f(rc[rr], rs[rr], cjA, sqA);
            float kB = (gi == gjB) ? 0.0f : kraw_f(rc[rr], rs[rr], cjB, sqB);
            float knA = kA * rv[rr];
            float knB = kB * rv[rr];
            float2 st = {knA, knB};
            *reinterpret_cast<float2*>(Kout + (size_t)gi * kN + gjA) = st;  // 256B/row coalesced
            __bf16 hA = (__bf16)knA, hB = (__bf16)knB;
            unsigned pk = ((unsigned)*(unsigned short*)&hB << 16) | *(unsigned short*)&hA;
            *reinterpret_cast<unsigned*>(&Alds[r][2 * c2]) = pk;
        }
        __syncthreads();

        // MFMA: A row-tiles {0,1} x B dim-tiles {0,1}; B direct from latTf
        #pragma unroll
        for (int kk = 0; kk < 2; ++kk) {
            const size_t jw = (size_t)(j0 >> 5) + kk;       // 32-col window index
            v8bf a0 = *reinterpret_cast<const v8bf*>(&Alds[arow][kk * 32 + koff]);
            v8bf a1 = *reinterpret_cast<const v8bf*>(&Alds[16 + arow][kk * 32 + koff]);
            v8bf b0 = *reinterpret_cast<const v8bf*>(bfb + (jw * 8 + wave * 2)     * 1024);
            v8bf b1 = *reinterpret_cast<const v8bf*>(bfb + (jw * 8 + wave * 2 + 1) * 1024);
            acc[0][0] = __builtin_amdgcn_mfma_f32_16x16x32_bf16(a0, b0, acc[0][0], 0, 0, 0);
            acc[0][1] = __builtin_amdgcn_mfma_f32_16x16x32_bf16(a0, b1, acc[0][1], 0, 0, 0);
            acc[1][0] = __builtin_amdgcn_mfma_f32_16x16x32_bf16(a1, b0, acc[1][0], 0, 0, 0);
            acc[1][1] = __builtin_amdgcn_mfma_f32_16x16x32_bf16(a1, b1, acc[1][1], 0, 0, 0);
        }
        __syncthreads();
    }

    // epilogue: D frag col = lane&15 (dim), row = (lane>>4)*4 + q  [m89 proven]
    const int row = (lane >> 4) * 4;
    const int col0 = wave * 32 + (lane & 15);
    #pragma unroll
    for (int rt = 0; rt < 2; ++rt)
        #pragma unroll
        for (int dt = 0; dt < 2; ++dt)
            #pragma unroll
            for (int q = 0; q < 4; ++q)
                atomicAdd(&outp[(size_t)(i0 + rt * 16 + row + q) * kD + col0 + dt * 16],
                          acc[rt][dt][q]);
}

extern "C" void kernel_launch(void* const* d_in, const int* in_sizes, int n_in,
                              void* d_out, int out_size, void* d_ws, size_t ws_size,
                              hipStream_t stream) {
    const float* latent = (const float*)d_in[0];
    const float* coords = (const float*)d_in[1];
    const float* alpha  = (const float*)d_in[2];

    float* outp = (float*)d_out;                    // [8192][128]
    float* Kout = (float*)d_out + (size_t)kN * kD;  // [8192][8192]

    // ws layout: byte-identical to the proven footprint.
    char* ws = (char*)d_ws;
    __bf16* latTf = (__bf16*)ws;                                  // 2 MiB
    float4* c4    = (float4*)(ws + 2u * 1024 * 1024);             // 128 KiB
    float*  rsum  = (float*)(ws + 2u * 1024 * 1024 + 128 * 1024); // 32 KiB

    pack_k<<<dim3(kN / 256), dim3(256), 0, stream>>>(coords, alpha, c4, rsum);
    fragprep_k<<<dim3(kN / 32), dim3(256), 0, stream>>>(latent, latTf, outp);
    rowsum_sym_k<<<dim3(NB * (NB + 1) / 2), dim3(256), 0, stream>>>(c4, rsum);
    main_k<<<dim3(kN / BM, JSPLIT), dim3(256), 0, stream>>>(c4, rsum, latTf, outp, Kout);
}